// Round 5
// baseline (485.533 us; speedup 1.0000x reference)
//
#include <hip/hip_runtime.h>

constexpr int BB = 2, HH = 16, LL = 2048, DD = 128;
constexpr int QB = 64, KB = 32, NKT = LL / KB;   // 64 k-tiles
constexpr float SCALE = 0.08838834764831845f;    // 1/sqrt(128)

typedef __attribute__((ext_vector_type(8))) short bf16x8;
typedef __attribute__((ext_vector_type(8))) unsigned short u16x8;
typedef __attribute__((ext_vector_type(4))) float f32x4;

static __device__ __forceinline__ unsigned short f2bf(float f) {
  unsigned int u = __builtin_bit_cast(unsigned int, f);
  u += 0x7fffu + ((u >> 16) & 1u);   // RNE
  return (unsigned short)(u >> 16);
}
static __device__ __forceinline__ int slotRC(int r) { return ((r >> 1) ^ (r >> 3)) & 3; }

#define GLD16(gsrc, ldst) __builtin_amdgcn_global_load_lds( \
    (const __attribute__((address_space(1))) void*)(gsrc), \
    (__attribute__((address_space(3))) void*)(ldst), 16, 0, 0)

// ---------------- prep ----------------
// Per (bh, 32-key tile): writes
//   kbT tile [16 dslots][32 keys][8 d]  (bf16)  -> linear-DMA, 2-way LDS reads
//   vtT tile [4 kc][128 d][8 keys]      (bf16)  -> linear-DMA, 2-way LDS reads
//   cpm = mask ? probs*alpha : -1e30    (f32, flat elementwise)
__global__ __launch_bounds__(256)
void prep_kernel(const float* __restrict__ k, const float* __restrict__ v,
                 const int* __restrict__ mask, const float* __restrict__ probs,
                 const float* __restrict__ alphap,
                 unsigned short* __restrict__ kbT, unsigned short* __restrict__ vtT,
                 float* __restrict__ cpm)
{
  __shared__ unsigned short sT[128 * 40];   // V^T tile, 80 B rows (16B-aligned slots)
  const int bid = blockIdx.x;
  const int bh = bid >> 6, kt = bid & 63;
  const int t = threadIdx.x;
  const float alpha = alphap[0];
  const size_t tileBase = (size_t)bid * 4096;   // bid == bh*64 + kt
  const float* kg = k + ((size_t)bh * LL + kt * 32) * DD;
  const float* vg = v + ((size_t)bh * LL + kt * 32) * DD;

  // K -> 16B-block-transposed tile
  #pragma unroll
  for (int s = t; s < 512; s += 256) {
    int dsl = s >> 5, key = s & 31;
    const float* src = kg + key * DD + dsl * 8;
    float4 a = *(const float4*)src;
    float4 c = *(const float4*)(src + 4);
    u16x8 w;
    w[0] = f2bf(a.x); w[1] = f2bf(a.y); w[2] = f2bf(a.z); w[3] = f2bf(a.w);
    w[4] = f2bf(c.x); w[5] = f2bf(c.y); w[6] = f2bf(c.z); w[7] = f2bf(c.w);
    *(u16x8*)(kbT + tileBase + (size_t)s * 8) = w;
  }
  // V -> sT (transpose)
  #pragma unroll
  for (int i = 0; i < 4; ++i) {
    int idx = i * 256 + t;
    int key = idx >> 5, d4 = (idx & 31) * 4;
    float4 x = ((const float4*)vg)[idx];
    sT[(d4 + 0) * 40 + key] = f2bf(x.x);
    sT[(d4 + 1) * 40 + key] = f2bf(x.y);
    sT[(d4 + 2) * 40 + key] = f2bf(x.z);
    sT[(d4 + 3) * 40 + key] = f2bf(x.w);
  }
  // cpm (flat)
  {
    const float4* ps = (const float4*)probs;
    const int4* ms = (const int4*)mask;
    float4* cs = (float4*)cpm;
    size_t base = (size_t)bid * 1024;
    #pragma unroll
    for (int i = 0; i < 4; ++i) {
      size_t idx = base + i * 256 + t;
      float4 p = ps[idx];
      int4 m = ms[idx];
      float4 o;
      o.x = m.x ? p.x * alpha : -1e30f;
      o.y = m.y ? p.y * alpha : -1e30f;
      o.z = m.z ? p.z * alpha : -1e30f;
      o.w = m.w ? p.w * alpha : -1e30f;
      cs[idx] = o;
    }
  }
  __syncthreads();
  // sT -> vtT tile [kc][d][8]
  #pragma unroll
  for (int s = t; s < 512; s += 256) {
    int kc = s >> 7, d = s & 127;
    u16x8 w = *(const u16x8*)&sT[d * 40 + kc * 8];
    *(u16x8*)(vtT + tileBase + (size_t)s * 8) = w;
  }
}

// ---------------- main fused attention ----------------
__global__ __launch_bounds__(512, 8)
void attn_kernel(const float* __restrict__ q, const unsigned short* __restrict__ kbT,
                 const unsigned short* __restrict__ vtT, const float* __restrict__ cpm,
                 float* __restrict__ outA, float* __restrict__ outP)
{
  __shared__ unsigned short sK[2][4096];    // 16 KB dbuf, tile [dslot][key][8]
  __shared__ unsigned short sVt[2][4096];   // 16 KB dbuf, tile [kc][d][8]
  __shared__ unsigned short sP[2048];       // 4 KB P tile (aliases sRed/sInv)
  float* sRedf = (float*)sP;
  float* sInvf = sRedf + 128;

  const int tid = threadIdx.x;
  const int lane = tid & 63;
  const int wid = tid >> 6;
  const int l15 = lane & 15;
  const int l4 = lane >> 4;
  const int wr = wid >> 1, wc = wid & 1;

  const int bid = blockIdx.x;
  const int qt = bid >> 5;
  const int bh = bid & 31;      // consecutive WGs share cpm rows (L2/L3 reuse)
  const int b = bh >> 4;
  const int q0 = qt * QB;

  const unsigned short* kbh = kbT + (size_t)bh * 64 * 4096;
  const unsigned short* vbh = vtT + (size_t)bh * 64 * 4096;
  const float* cg = cpm + (size_t)b * LL * LL + (size_t)q0 * LL;
  float* oA = outA + (size_t)(bh * LL + q0) * DD;
  float* oP = outP + (size_t)bh * LL * LL + (size_t)q0 * LL;

  const int qrow = wr * 16 + l15;     // wave's q-row for A-frags
  const int keyloc = wc * 16 + l15;   // wave's key column (QK B-frag)
  const int row0 = wr * 16 + l4 * 4;  // acc row base

  // ---- Q fragments straight from global (one-time, ~32 B/lane/frag) ----
  bf16x8 qf0, qf1, qf2, qf3;
  {
    const float* qs = q + (size_t)(bh * LL + q0 + qrow) * DD + l4 * 8;
    #define LQ(FR, KC) { \
      float4 a = *(const float4*)(qs + (KC) * 32); \
      float4 c = *(const float4*)(qs + (KC) * 32 + 4); \
      FR[0]=(short)f2bf(a.x); FR[1]=(short)f2bf(a.y); FR[2]=(short)f2bf(a.z); FR[3]=(short)f2bf(a.w); \
      FR[4]=(short)f2bf(c.x); FR[5]=(short)f2bf(c.y); FR[6]=(short)f2bf(c.z); FR[7]=(short)f2bf(c.w); }
    LQ(qf0, 0) LQ(qf1, 1) LQ(qf2, 2) LQ(qf3, 3)
    #undef LQ
  }

  const int ldsW = wid << 9;   // u16 elements: 1 KB per wave
  #define DMA_K(BUF, KT) GLD16(kbh + (size_t)(KT) * 4096 + tid * 8, &sK[BUF][ldsW])
  #define DMA_V(BUF, KT) GLD16(vbh + (size_t)(KT) * 4096 + tid * 8, &sVt[BUF][ldsW])

  #define QKSTEP(KC, QF) { \
    bf16x8 bK = *(const bf16x8*)&sK[cur][(((KC) * 4 + l4) * 32 + keyloc) * 8]; \
    acc = __builtin_amdgcn_mfma_f32_16x16x32_bf16(QF, bK, acc, 0, 0, 0); }

  // =================== PASS A: rowsums ===================
  int co0 = (row0 + 0) * LL + keyloc;
  int co1 = co0 + LL, co2 = co1 + LL, co3 = co2 + LL;
  DMA_K(0, 0);
  float cn0 = cg[co0], cn1 = cg[co1], cn2 = cg[co2], cn3 = cg[co3];
  float sum0 = 0.f, sum1 = 0.f, sum2 = 0.f, sum3 = 0.f;
  for (int kt = 0; kt < NKT; ++kt) {
    const int cur = kt & 1;
    __syncthreads();                       // sK[cur] + cn* resident
    if (kt + 1 < NKT) DMA_K(cur ^ 1, kt + 1);
    float b0 = cn0, b1 = cn1, b2 = cn2, b3 = cn3;
    co0 += KB; co1 += KB; co2 += KB; co3 += KB;
    if (kt + 1 < NKT) { cn0 = cg[co0]; cn1 = cg[co1]; cn2 = cg[co2]; cn3 = cg[co3]; }
    f32x4 acc = {0.f, 0.f, 0.f, 0.f};
    QKSTEP(0, qf0) QKSTEP(1, qf1) QKSTEP(2, qf2) QKSTEP(3, qf3)
    sum0 += __expf(acc[0] * SCALE + b0);
    sum1 += __expf(acc[1] * SCALE + b1);
    sum2 += __expf(acc[2] * SCALE + b2);
    sum3 += __expf(acc[3] * SCALE + b3);
  }

  #pragma unroll
  for (int m = 1; m < 16; m <<= 1) {
    sum0 += __shfl_xor(sum0, m, 64);
    sum1 += __shfl_xor(sum1, m, 64);
    sum2 += __shfl_xor(sum2, m, 64);
    sum3 += __shfl_xor(sum3, m, 64);
  }
  __syncthreads();
  if (l15 == 0) {
    sRedf[(row0 + 0) * 2 + wc] = sum0;
    sRedf[(row0 + 1) * 2 + wc] = sum1;
    sRedf[(row0 + 2) * 2 + wc] = sum2;
    sRedf[(row0 + 3) * 2 + wc] = sum3;
  }
  __syncthreads();
  if (tid < QB) sInvf[tid] = 1.0f / (sRedf[tid * 2] + sRedf[tid * 2 + 1]);
  __syncthreads();
  const float inv0 = sInvf[row0 + 0], inv1 = sInvf[row0 + 1],
              inv2 = sInvf[row0 + 2], inv3 = sInvf[row0 + 3];

  // =================== PASS B: attn_p + O ===================
  co0 = (row0 + 0) * LL + keyloc;
  co1 = co0 + LL; co2 = co1 + LL; co3 = co2 + LL;
  DMA_K(0, 0); DMA_V(0, 0);
  cn0 = cg[co0]; cn1 = cg[co1]; cn2 = cg[co2]; cn3 = cg[co3];
  f32x4 o0 = {0,0,0,0}, o1 = {0,0,0,0}, o2 = {0,0,0,0}, o3 = {0,0,0,0};
  for (int kt = 0; kt < NKT; ++kt) {
    const int cur = kt & 1;
    __syncthreads();                       // sK/sVt[cur] + cn* resident; sP free
    if (kt + 1 < NKT) { DMA_K(cur ^ 1, kt + 1); DMA_V(cur ^ 1, kt + 1); }
    float b0 = cn0, b1 = cn1, b2 = cn2, b3 = cn3;
    co0 += KB; co1 += KB; co2 += KB; co3 += KB;
    if (kt + 1 < NKT) { cn0 = cg[co0]; cn1 = cg[co1]; cn2 = cg[co2]; cn3 = cg[co3]; }
    f32x4 acc = {0.f, 0.f, 0.f, 0.f};
    QKSTEP(0, qf0) QKSTEP(1, qf1) QKSTEP(2, qf2) QKSTEP(3, qf3)
    float e0 = __expf(acc[0] * SCALE + b0) * inv0;
    float e1 = __expf(acc[1] * SCALE + b1) * inv1;
    float e2 = __expf(acc[2] * SCALE + b2) * inv2;
    float e3 = __expf(acc[3] * SCALE + b3) * inv3;
    const int keyg = kt * KB + keyloc;
    oP[(size_t)(row0 + 0) * LL + keyg] = e0;
    oP[(size_t)(row0 + 1) * LL + keyg] = e1;
    oP[(size_t)(row0 + 2) * LL + keyg] = e2;
    oP[(size_t)(row0 + 3) * LL + keyg] = e3;
    sP[(row0 + 0) * KB + (keyloc ^ (slotRC(row0 + 0) << 3))] = f2bf(e0);
    sP[(row0 + 1) * KB + (keyloc ^ (slotRC(row0 + 1) << 3))] = f2bf(e1);
    sP[(row0 + 2) * KB + (keyloc ^ (slotRC(row0 + 2) << 3))] = f2bf(e2);
    sP[(row0 + 3) * KB + (keyloc ^ (slotRC(row0 + 3) << 3))] = f2bf(e3);
    // mid barrier: LDS visibility only — DMA + cpm prefetch stay in flight
    asm volatile("s_waitcnt lgkmcnt(0)\n\ts_barrier" ::: "memory");
    bf16x8 aP = *(const bf16x8*)&sP[qrow * KB + ((l4 * 8) ^ (slotRC(qrow) << 3))];
    #define PVSTEP(DT, OO) { \
      int dcol = wc * 64 + (DT) * 16 + l15; \
      bf16x8 bV = *(const bf16x8*)&sVt[cur][(l4 * 128 + dcol) * 8]; \
      OO = __builtin_amdgcn_mfma_f32_16x16x32_bf16(aP, bV, OO, 0, 0, 0); }
    PVSTEP(0, o0) PVSTEP(1, o1) PVSTEP(2, o2) PVSTEP(3, o3)
    #undef PVSTEP
  }

  // ---- store attention ----
  #pragma unroll
  for (int r = 0; r < 4; ++r) {
    float* dst = oA + (size_t)(row0 + r) * DD + wc * 64 + l15;
    dst[0]  = o0[r];
    dst[16] = o1[r];
    dst[32] = o2[r];
    dst[48] = o3[r];
  }
}

extern "C" void kernel_launch(void* const* d_in, const int* in_sizes, int n_in,
                              void* d_out, int out_size, void* d_ws, size_t ws_size,
                              hipStream_t stream) {
  const float* q = (const float*)d_in[0];
  const float* k = (const float*)d_in[1];
  const float* v = (const float*)d_in[2];
  const int* mask = (const int*)d_in[3];
  const float* probs = (const float*)d_in[4];
  const float* alpha = (const float*)d_in[5];
  float* outA = (float*)d_out;
  float* outP = outA + (size_t)BB * HH * LL * DD;
  unsigned short* kbT = (unsigned short*)d_ws;
  unsigned short* vtT = kbT + (size_t)32 * 64 * 4096;
  float* cpm = (float*)(vtT + (size_t)32 * 64 * 4096);
  hipLaunchKernelGGL(prep_kernel, dim3(32 * 64), dim3(256), 0, stream,
                     k, v, mask, probs, alpha, kbT, vtT, cpm);
  hipLaunchKernelGGL(attn_kernel, dim3(BB * HH * (LL / QB)), dim3(512), 0, stream,
                     q, kbT, vtT, cpm, outA, outP);
}

// Round 6
// 383.404 us; speedup vs baseline: 1.2664x; 1.2664x over previous
//
#include <hip/hip_runtime.h>

constexpr int BB = 2, HH = 16, LL = 2048, DD = 128;
constexpr int QB = 64, KB = 32, NKT = LL / KB;   // 64 k-tiles
constexpr float SCALE = 0.08838834764831845f;    // 1/sqrt(128)

typedef __attribute__((ext_vector_type(8))) short bf16x8;
typedef __attribute__((ext_vector_type(8))) unsigned short u16x8;
typedef __attribute__((ext_vector_type(4))) float f32x4;

static __device__ __forceinline__ unsigned short f2bf(float f) {
  unsigned int u = __builtin_bit_cast(unsigned int, f);
  u += 0x7fffu + ((u >> 16) & 1u);   // RNE
  return (unsigned short)(u >> 16);
}
static __device__ __forceinline__ int slotRC(int r) { return ((r >> 1) ^ (r >> 3)) & 3; }

#define GLD16(gsrc, ldst) __builtin_amdgcn_global_load_lds( \
    (const __attribute__((address_space(1))) void*)(gsrc), \
    (__attribute__((address_space(3))) void*)(ldst), 16, 0, 0)

// ---------------- prep ----------------
// Per (bh, 32-key tile): writes
//   kbT tile [16 dslots][32 keys][8 d]  (bf16)  -> linear-DMA, 2-way LDS reads
//   vtT tile [4 kc][128 d][8 keys]      (bf16)  -> linear-DMA, 2-way LDS reads
//   cpm = mask ? probs*alpha : -1e30    (f32, flat elementwise)
__global__ __launch_bounds__(256)
void prep_kernel(const float* __restrict__ k, const float* __restrict__ v,
                 const int* __restrict__ mask, const float* __restrict__ probs,
                 const float* __restrict__ alphap,
                 unsigned short* __restrict__ kbT, unsigned short* __restrict__ vtT,
                 float* __restrict__ cpm)
{
  __shared__ unsigned short sT[128 * 40];   // V^T tile, 80 B rows (16B-aligned slots)
  const int bid = blockIdx.x;
  const int bh = bid >> 6, kt = bid & 63;
  const int t = threadIdx.x;
  const float alpha = alphap[0];
  const size_t tileBase = (size_t)bid * 4096;   // bid == bh*64 + kt
  const float* kg = k + ((size_t)bh * LL + kt * 32) * DD;
  const float* vg = v + ((size_t)bh * LL + kt * 32) * DD;

  // K -> 16B-block-transposed tile
  #pragma unroll
  for (int s = t; s < 512; s += 256) {
    int dsl = s >> 5, key = s & 31;
    const float* src = kg + key * DD + dsl * 8;
    float4 a = *(const float4*)src;
    float4 c = *(const float4*)(src + 4);
    u16x8 w;
    w[0] = f2bf(a.x); w[1] = f2bf(a.y); w[2] = f2bf(a.z); w[3] = f2bf(a.w);
    w[4] = f2bf(c.x); w[5] = f2bf(c.y); w[6] = f2bf(c.z); w[7] = f2bf(c.w);
    *(u16x8*)(kbT + tileBase + (size_t)s * 8) = w;
  }
  // V -> sT (transpose)
  #pragma unroll
  for (int i = 0; i < 4; ++i) {
    int idx = i * 256 + t;
    int key = idx >> 5, d4 = (idx & 31) * 4;
    float4 x = ((const float4*)vg)[idx];
    sT[(d4 + 0) * 40 + key] = f2bf(x.x);
    sT[(d4 + 1) * 40 + key] = f2bf(x.y);
    sT[(d4 + 2) * 40 + key] = f2bf(x.z);
    sT[(d4 + 3) * 40 + key] = f2bf(x.w);
  }
  // cpm (flat)
  {
    const float4* ps = (const float4*)probs;
    const int4* ms = (const int4*)mask;
    float4* cs = (float4*)cpm;
    size_t base = (size_t)bid * 1024;
    #pragma unroll
    for (int i = 0; i < 4; ++i) {
      size_t idx = base + i * 256 + t;
      float4 p = ps[idx];
      int4 m = ms[idx];
      float4 o;
      o.x = m.x ? p.x * alpha : -1e30f;
      o.y = m.y ? p.y * alpha : -1e30f;
      o.z = m.z ? p.z * alpha : -1e30f;
      o.w = m.w ? p.w * alpha : -1e30f;
      cs[idx] = o;
    }
  }
  __syncthreads();
  // sT -> vtT tile [kc][d][8]
  #pragma unroll
  for (int s = t; s < 512; s += 256) {
    int kc = s >> 7, d = s & 127;
    u16x8 w = *(const u16x8*)&sT[d * 40 + kc * 8];
    *(u16x8*)(vtT + tileBase + (size_t)s * 8) = w;
  }
}

// ---------------- main fused attention ----------------
__global__ __launch_bounds__(512, 8)
void attn_kernel(const float* __restrict__ q, const unsigned short* __restrict__ kbT,
                 const unsigned short* __restrict__ vtT, const float* __restrict__ cpm,
                 float* __restrict__ outA, float* __restrict__ outP)
{
  __shared__ unsigned short sK[2][4096];    // 16 KB dbuf, tile [dslot][key][8]
  __shared__ unsigned short sVt[2][4096];   // 16 KB dbuf, tile [kc][d][8]
  __shared__ unsigned short sP[2048];       // 4 KB P tile (aliases sRed/sInv)
  float* sRedf = (float*)sP;
  float* sInvf = sRedf + 128;

  const int tid = threadIdx.x;
  const int lane = tid & 63;
  const int wid = tid >> 6;
  const int l15 = lane & 15;
  const int l4 = lane >> 4;
  const int wr = wid >> 1, wc = wid & 1;

  // XCD-chunked swizzle: XCD x (= bid%8) owns work items [x*128, x*128+128)
  // bh-major decode: each XCD touches only 4 bh -> K+V ws (4 MB) fits its L2.
  const int bid = blockIdx.x;
  const int work = ((bid & 7) << 7) | (bid >> 3);
  const int bh = work >> 5;     // 0..31
  const int qt = work & 31;     // 0..31
  const int b = bh >> 4;
  const int q0 = qt * QB;

  const unsigned short* kbh = kbT + (size_t)bh * 64 * 4096;
  const unsigned short* vbh = vtT + (size_t)bh * 64 * 4096;
  const float* cg = cpm + (size_t)b * LL * LL + (size_t)q0 * LL;
  float* oA = outA + (size_t)(bh * LL + q0) * DD;
  float* oP = outP + (size_t)bh * LL * LL + (size_t)q0 * LL;

  const int qrow = wr * 16 + l15;     // wave's q-row for A-frags
  const int keyloc = wc * 16 + l15;   // wave's key column (QK B-frag)
  const int row0 = wr * 16 + l4 * 4;  // acc row base

  // ---- Q fragments straight from global (one-time) ----
  bf16x8 qf0, qf1, qf2, qf3;
  {
    const float* qs = q + (size_t)(bh * LL + q0 + qrow) * DD + l4 * 8;
    #define LQ(FR, KC) { \
      float4 a = *(const float4*)(qs + (KC) * 32); \
      float4 c = *(const float4*)(qs + (KC) * 32 + 4); \
      FR[0]=(short)f2bf(a.x); FR[1]=(short)f2bf(a.y); FR[2]=(short)f2bf(a.z); FR[3]=(short)f2bf(a.w); \
      FR[4]=(short)f2bf(c.x); FR[5]=(short)f2bf(c.y); FR[6]=(short)f2bf(c.z); FR[7]=(short)f2bf(c.w); }
    LQ(qf0, 0) LQ(qf1, 1) LQ(qf2, 2) LQ(qf3, 3)
    #undef LQ
  }

  const int ldsW = wid << 9;   // u16 elements: 1 KB per wave
  #define DMA_K(BUF, KT) GLD16(kbh + (size_t)(KT) * 4096 + tid * 8, &sK[BUF][ldsW])
  #define DMA_V(BUF, KT) GLD16(vbh + (size_t)(KT) * 4096 + tid * 8, &sVt[BUF][ldsW])

  #define QKSTEP(KC, QF) { \
    bf16x8 bK = *(const bf16x8*)&sK[cur][(((KC) * 4 + l4) * 32 + keyloc) * 8]; \
    acc = __builtin_amdgcn_mfma_f32_16x16x32_bf16(QF, bK, acc, 0, 0, 0); }

  // =================== PASS A: rowsums ===================
  int co0 = (row0 + 0) * LL + keyloc;
  int co1 = co0 + LL, co2 = co1 + LL, co3 = co2 + LL;
  DMA_K(0, 0);
  float cn0 = cg[co0], cn1 = cg[co1], cn2 = cg[co2], cn3 = cg[co3];
  float sum0 = 0.f, sum1 = 0.f, sum2 = 0.f, sum3 = 0.f;
  for (int kt = 0; kt < NKT; ++kt) {
    const int cur = kt & 1;
    __syncthreads();                       // sK[cur] + cn* resident
    if (kt + 1 < NKT) DMA_K(cur ^ 1, kt + 1);
    float b0 = cn0, b1 = cn1, b2 = cn2, b3 = cn3;
    co0 += KB; co1 += KB; co2 += KB; co3 += KB;
    if (kt + 1 < NKT) { cn0 = cg[co0]; cn1 = cg[co1]; cn2 = cg[co2]; cn3 = cg[co3]; }
    f32x4 acc = {0.f, 0.f, 0.f, 0.f};
    QKSTEP(0, qf0) QKSTEP(1, qf1) QKSTEP(2, qf2) QKSTEP(3, qf3)
    sum0 += __expf(acc[0] * SCALE + b0);
    sum1 += __expf(acc[1] * SCALE + b1);
    sum2 += __expf(acc[2] * SCALE + b2);
    sum3 += __expf(acc[3] * SCALE + b3);
  }

  #pragma unroll
  for (int m = 1; m < 16; m <<= 1) {
    sum0 += __shfl_xor(sum0, m, 64);
    sum1 += __shfl_xor(sum1, m, 64);
    sum2 += __shfl_xor(sum2, m, 64);
    sum3 += __shfl_xor(sum3, m, 64);
  }
  __syncthreads();
  if (l15 == 0) {
    sRedf[(row0 + 0) * 2 + wc] = sum0;
    sRedf[(row0 + 1) * 2 + wc] = sum1;
    sRedf[(row0 + 2) * 2 + wc] = sum2;
    sRedf[(row0 + 3) * 2 + wc] = sum3;
  }
  __syncthreads();
  if (tid < QB) sInvf[tid] = 1.0f / (sRedf[tid * 2] + sRedf[tid * 2 + 1]);
  __syncthreads();
  const float inv0 = sInvf[row0 + 0], inv1 = sInvf[row0 + 1],
              inv2 = sInvf[row0 + 2], inv3 = sInvf[row0 + 3];

  // =================== PASS B: attn_p + O ===================
  co0 = (row0 + 0) * LL + keyloc;
  co1 = co0 + LL; co2 = co1 + LL; co3 = co2 + LL;
  DMA_K(0, 0); DMA_V(0, 0);
  cn0 = cg[co0]; cn1 = cg[co1]; cn2 = cg[co2]; cn3 = cg[co3];
  f32x4 o0 = {0,0,0,0}, o1 = {0,0,0,0}, o2 = {0,0,0,0}, o3 = {0,0,0,0};
  for (int kt = 0; kt < NKT; ++kt) {
    const int cur = kt & 1;
    __syncthreads();                       // sK/sVt[cur] + cn* resident; sP free
    if (kt + 1 < NKT) { DMA_K(cur ^ 1, kt + 1); DMA_V(cur ^ 1, kt + 1); }
    float b0 = cn0, b1 = cn1, b2 = cn2, b3 = cn3;
    co0 += KB; co1 += KB; co2 += KB; co3 += KB;
    if (kt + 1 < NKT) { cn0 = cg[co0]; cn1 = cg[co1]; cn2 = cg[co2]; cn3 = cg[co3]; }
    f32x4 acc = {0.f, 0.f, 0.f, 0.f};
    QKSTEP(0, qf0) QKSTEP(1, qf1) QKSTEP(2, qf2) QKSTEP(3, qf3)
    float e0 = __expf(acc[0] * SCALE + b0) * inv0;
    float e1 = __expf(acc[1] * SCALE + b1) * inv1;
    float e2 = __expf(acc[2] * SCALE + b2) * inv2;
    float e3 = __expf(acc[3] * SCALE + b3) * inv3;
    const int keyg = kt * KB + keyloc;
    // non-temporal: keep the 537 MB attn_p stream from evicting L2/L3 reads
    __builtin_nontemporal_store(e0, &oP[(size_t)(row0 + 0) * LL + keyg]);
    __builtin_nontemporal_store(e1, &oP[(size_t)(row0 + 1) * LL + keyg]);
    __builtin_nontemporal_store(e2, &oP[(size_t)(row0 + 2) * LL + keyg]);
    __builtin_nontemporal_store(e3, &oP[(size_t)(row0 + 3) * LL + keyg]);
    sP[(row0 + 0) * KB + (keyloc ^ (slotRC(row0 + 0) << 3))] = f2bf(e0);
    sP[(row0 + 1) * KB + (keyloc ^ (slotRC(row0 + 1) << 3))] = f2bf(e1);
    sP[(row0 + 2) * KB + (keyloc ^ (slotRC(row0 + 2) << 3))] = f2bf(e2);
    sP[(row0 + 3) * KB + (keyloc ^ (slotRC(row0 + 3) << 3))] = f2bf(e3);
    // mid barrier: LDS visibility only — DMA + cpm prefetch stay in flight
    asm volatile("s_waitcnt lgkmcnt(0)\n\ts_barrier" ::: "memory");
    bf16x8 aP = *(const bf16x8*)&sP[qrow * KB + ((l4 * 8) ^ (slotRC(qrow) << 3))];
    #define PVSTEP(DT, OO) { \
      int dcol = wc * 64 + (DT) * 16 + l15; \
      bf16x8 bV = *(const bf16x8*)&sVt[cur][(l4 * 128 + dcol) * 8]; \
      OO = __builtin_amdgcn_mfma_f32_16x16x32_bf16(aP, bV, OO, 0, 0, 0); }
    PVSTEP(0, o0) PVSTEP(1, o1) PVSTEP(2, o2) PVSTEP(3, o3)
    #undef PVSTEP
  }

  // ---- store attention (non-temporal) ----
  #pragma unroll
  for (int r = 0; r < 4; ++r) {
    float* dst = oA + (size_t)(row0 + r) * DD + wc * 64 + l15;
    __builtin_nontemporal_store(o0[r], dst);
    __builtin_nontemporal_store(o1[r], dst + 16);
    __builtin_nontemporal_store(o2[r], dst + 32);
    __builtin_nontemporal_store(o3[r], dst + 48);
  }
}

extern "C" void kernel_launch(void* const* d_in, const int* in_sizes, int n_in,
                              void* d_out, int out_size, void* d_ws, size_t ws_size,
                              hipStream_t stream) {
  const float* q = (const float*)d_in[0];
  const float* k = (const float*)d_in[1];
  const float* v = (const float*)d_in[2];
  const int* mask = (const int*)d_in[3];
  const float* probs = (const float*)d_in[4];
  const float* alpha = (const float*)d_in[5];
  float* outA = (float*)d_out;
  float* outP = outA + (size_t)BB * HH * LL * DD;
  unsigned short* kbT = (unsigned short*)d_ws;
  unsigned short* vtT = kbT + (size_t)32 * 64 * 4096;
  float* cpm = (float*)(vtT + (size_t)32 * 64 * 4096);
  hipLaunchKernelGGL(prep_kernel, dim3(32 * 64), dim3(256), 0, stream,
                     k, v, mask, probs, alpha, kbT, vtT, cpm);
  hipLaunchKernelGGL(attn_kernel, dim3(BB * HH * (LL / QB)), dim3(512), 0, stream,
                     q, kbT, vtT, cpm, outA, outP);
}